// Round 20
// baseline (113.440 us; speedup 1.0000x reference)
//
#include <hip/hip_runtime.h>

// Fused MHA: x->QKV proj (bf16 MFMA) -> causal flash attn -> O proj.
// B=2, T=2048, D=1024, H=16, HD=64.
// Round 20: r18 base + FIXED dual-step: single per-wave lp buffer used
// sequentially (B then A) inside the fused step — shared kf QK loads and
// shared vf PV loads, no cross-wave buffer aliasing (r19's race).

#define DEV __device__ __forceinline__

typedef __attribute__((ext_vector_type(8))) __bf16 bf16x8;
typedef __attribute__((ext_vector_type(4))) float f32x4;

DEV unsigned short f2bf(float f) {
  union { float f; unsigned u; } c;
  c.f = f;
  unsigned u = c.u + 0x7FFFu + ((c.u >> 16) & 1u);  // RTNE
  return (unsigned short)(u >> 16);
}

DEV unsigned cvtpk(float lo, float hi) {
  unsigned r;
  asm("v_cvt_pk_bf16_f32 %0, %1, %2" : "=v"(r) : "v"(lo), "v"(hi));
  return r;
}

DEV void gload16(const unsigned short* g, unsigned short* l) {
  __builtin_amdgcn_global_load_lds(
      (const __attribute__((address_space(1))) unsigned int*)g,
      (__attribute__((address_space(3))) unsigned int*)l, 16, 0, 0);
}

DEV f32x4 mfma16(bf16x8 a, bf16x8 b, f32x4 c) {
  return __builtin_amdgcn_mfma_f32_16x16x32_bf16(a, b, c, 0, 0, 0);
}

#define WAITVM(n) asm volatile("s_waitcnt vmcnt(" #n ")" ::: "memory")
#define WAITLGKM() asm volatile("s_waitcnt lgkmcnt(0)" ::: "memory")
#define BAR() __builtin_amdgcn_s_barrier()
#define SCHEDB() __builtin_amdgcn_sched_barrier(0)
#define PRIO(n) __builtin_amdgcn_s_setprio(n)

// ---------------- fp32 -> bf16 convert (all 5 tensors, one launch) -------
__global__ __launch_bounds__(256) void k_cvt_all(
    const float* __restrict__ x, const float* __restrict__ wq,
    const float* __restrict__ wk, const float* __restrict__ wv,
    const float* __restrict__ wo, unsigned short* __restrict__ dst) {
  int i = blockIdx.x * blockDim.x + threadIdx.x;  // float4 index
  const float* s;
  int off;
  if (i < 1048576) {
    s = x; off = i;
  } else {
    int j = i - 1048576;
    int w = j >> 18;
    off = j & 262143;
    s = (w == 0) ? wq : (w == 1) ? wk : (w == 2) ? wv : wo;
  }
  float4 v = reinterpret_cast<const float4*>(s)[off];
  uint2 o;
  o.x = (unsigned)f2bf(v.x) | ((unsigned)f2bf(v.y) << 16);
  o.y = (unsigned)f2bf(v.z) | ((unsigned)f2bf(v.w) << 16);
  reinterpret_cast<uint2*>(dst)[i] = o;
}

// ---------------- FUSED QKV projection (128x64 tiles, 3 modes) ----------
__global__ __launch_bounds__(256) void k_gemm_qkv(
    const unsigned short* __restrict__ X, const unsigned short* __restrict__ Wq,
    const unsigned short* __restrict__ Wk, const unsigned short* __restrict__ Wv,
    const float* __restrict__ bq, const float* __restrict__ bk,
    const float* __restrict__ bv, unsigned short* __restrict__ Qo,
    unsigned short* __restrict__ Ko, unsigned short* __restrict__ Vo) {
  __shared__ unsigned short ls[20480];  // X 2x4096 | Wq 2x2048 | Wk | Wv
  unsigned short* la0 = ls;
  unsigned short* lbq = ls + 8192;
  unsigned short* lbk = ls + 12288;
  unsigned short* lbv = ls + 16384;

  const int id = blockIdx.x;
  const int xcd = id & 7, s4 = id >> 3;
  const int bx = ((s4 >> 3) & 7) * 2 + (xcd & 1);  // 0..15
  const int by = (s4 & 7) * 4 + (xcd >> 1);        // 0..31
  const int m0 = by * 128, n0 = bx * 64;

  const int tid = threadIdx.x;
  const int lane = tid & 63, wave = tid >> 6;
  const int l15 = lane & 15, g = lane >> 4;
  const int wm = (wave >> 1) * 64, wn = (wave & 1) * 32;
  const int g16 = g << 4;
  const int sx = (lane & 3) << 4;

  f32x4 a0[4][2] = {}, a1[4][2] = {}, a2[4][2] = {};

#define STG_QKV(buf, k0)                                                     \
  {                                                                          \
    _Pragma("unroll") for (int i = 0; i < 2; ++i) {                          \
      const int c = i * 256 + tid;                                           \
      const int row = c >> 2;                                                \
      const int scb = ((c & 3) << 4) ^ ((row & 3) << 4);                     \
      gload16(X + (m0 + row) * 1024 + (k0) + (scb >> 1),                     \
              (unsigned short*)((char*)(la0 + (buf)*4096) + c * 16));        \
    }                                                                        \
    {                                                                        \
      const int row = tid >> 2;                                              \
      const int scb = ((tid & 3) << 4) ^ ((row & 3) << 4);                   \
      const int go = (n0 + row) * 1024 + (k0) + (scb >> 1);                  \
      gload16(Wq + go,                                                       \
              (unsigned short*)((char*)(lbq + (buf)*2048) + tid * 16));      \
      gload16(Wk + go,                                                       \
              (unsigned short*)((char*)(lbk + (buf)*2048) + tid * 16));      \
      gload16(Wv + go,                                                       \
              (unsigned short*)((char*)(lbv + (buf)*2048) + tid * 16));      \
    }                                                                        \
  }

  STG_QKV(0, 0);
  __syncthreads();

  for (int kt = 0; kt < 32; ++kt) {
    const int cur = kt & 1;
    if (kt + 1 < 32) STG_QKV(cur ^ 1, (kt + 1) * 32);
    unsigned short* la = la0 + cur * 4096;
    bf16x8 af[4];
#pragma unroll
    for (int m = 0; m < 4; ++m)
      af[m] = *reinterpret_cast<const bf16x8*>(
          (char*)la + (wm + m * 16 + l15) * 64 + (g16 ^ sx));
    {
      unsigned short* lb = lbq + cur * 2048;
      bf16x8 bfr[2];
#pragma unroll
      for (int n = 0; n < 2; ++n)
        bfr[n] = *reinterpret_cast<const bf16x8*>(
            (char*)lb + (wn + n * 16 + l15) * 64 + (g16 ^ sx));
#pragma unroll
      for (int m = 0; m < 4; ++m)
#pragma unroll
        for (int n = 0; n < 2; ++n) a0[m][n] = mfma16(af[m], bfr[n], a0[m][n]);
    }
    {
      unsigned short* lb = lbk + cur * 2048;
      bf16x8 bfr[2];
#pragma unroll
      for (int n = 0; n < 2; ++n)
        bfr[n] = *reinterpret_cast<const bf16x8*>(
            (char*)lb + (wn + n * 16 + l15) * 64 + (g16 ^ sx));
#pragma unroll
      for (int m = 0; m < 4; ++m)
#pragma unroll
        for (int n = 0; n < 2; ++n) a1[m][n] = mfma16(af[m], bfr[n], a1[m][n]);
    }
    {
      unsigned short* lb = lbv + cur * 2048;
      bf16x8 bfr[2];
#pragma unroll
      for (int n = 0; n < 2; ++n)
        bfr[n] = *reinterpret_cast<const bf16x8*>(
            (char*)lb + (wn + n * 16 + l15) * 64 + (g16 ^ sx));
#pragma unroll
      for (int m = 0; m < 4; ++m)
#pragma unroll
        for (int n = 0; n < 2; ++n) a2[m][n] = mfma16(af[m], bfr[n], a2[m][n]);
    }
    __syncthreads();
  }
#undef STG_QKV

  // ---- epilogues (per-wave 4KB lw; modes sequential with lgkm fences) ----
  unsigned short* lw = ls + wave * 2048;
  const int h = (n0 + wn) >> 6;
  const int hd0 = (n0 + wn) & 63;       // 0 or 32
  const int rb = m0 + wm;
  const int b = rb >> 11;
  const int tb0 = rb & 2047;

  // Q (scaled) then K: lw[64 t][32 hd]
#pragma unroll
  for (int mode = 0; mode < 2; ++mode) {
    const float* bias = mode ? bk : bq;
    const float sc = mode ? 1.0f : 0.180336880f;  // 0.125 * log2(e)
    unsigned short* dst = mode ? Ko : Qo;
    WAITLGKM();  // prior mode's lw reads complete before overwrite
#pragma unroll
    for (int m = 0; m < 4; ++m)
#pragma unroll
      for (int n = 0; n < 2; ++n) {
        const float bb = bias[n0 + wn + n * 16 + l15];
        const f32x4 av = mode ? a1[m][n] : a0[m][n];
#pragma unroll
        for (int r = 0; r < 4; ++r)
          lw[(m * 16 + (g << 2) + r) * 32 + n * 16 + l15] =
              f2bf((av[r] + bb) * sc);
      }
    WAITLGKM();
    SCHEDB();
#pragma unroll
    for (int it = 0; it < 4; ++it) {
      const int rr = (lane >> 2) + it * 16;
      const int ck = (lane & 3) * 8;
      uint4 v = *reinterpret_cast<const uint4*>(&lw[rr * 32 + ck]);
      *reinterpret_cast<uint4*>(
          &dst[(((b << 4) + h) * 2048 + tb0 + rr) * 64 + hd0 + ck]) = v;
    }
  }

  // V^T: lw[32 hd][64 t]
  WAITLGKM();
#pragma unroll
  for (int m = 0; m < 4; ++m)
#pragma unroll
    for (int n = 0; n < 2; ++n) {
      const float bb = bv[n0 + wn + n * 16 + l15];
      uint2 w;
      w.x = cvtpk(a2[m][n][0] + bb, a2[m][n][1] + bb);
      w.y = cvtpk(a2[m][n][2] + bb, a2[m][n][3] + bb);
      *reinterpret_cast<uint2*>(&lw[(n * 16 + l15) * 64 + m * 16 + (g << 2)]) =
          w;
    }
  WAITLGKM();
  SCHEDB();
#pragma unroll
  for (int it = 0; it < 4; ++it) {
    const int hdr = (lane >> 3) + it * 8;
    const int ck = (lane & 7) * 8;
    uint4 v = *reinterpret_cast<const uint4*>(&lw[hdr * 64 + ck]);
    *reinterpret_cast<uint4*>(
        &Vo[(((b << 4) + h) * 64 + hd0 + hdr) * 2048 + tb0 + ck]) = v;
  }
}

// ---------------- output projection (128x64 tiles, fp32 out + bias) ------
__global__ __launch_bounds__(256) void k_gemm_out(
    const unsigned short* __restrict__ Ctx, const unsigned short* __restrict__ Wo,
    const float* __restrict__ bo, float* __restrict__ Out) {
  __shared__ unsigned short ls[16384];
  unsigned short* la0 = ls;
  unsigned short* lb0 = ls + 8192;
  const int id = blockIdx.x;
  const int xcd = id & 7, s4 = id >> 3;            // s4: 0..63
  const int bx = ((s4 >> 3) & 7) * 2 + (xcd & 1);  // 0..15
  const int by = (s4 & 7) * 4 + (xcd >> 1);        // 0..31
  const int tid = threadIdx.x;
  const int lane = tid & 63, wave = tid >> 6;
  const int l15 = lane & 15, g = lane >> 4;
  const int m0 = by * 128, n0 = bx * 64;
  const int wm = (wave >> 1) * 64, wn = (wave & 1) * 32;
  const int g16 = (g << 4);
  const int sx = (lane & 3) << 4;
  f32x4 acc[4][2] = {};

#define STG_OUT(buf, k0)                                                     \
  {                                                                          \
    _Pragma("unroll") for (int i = 0; i < 2; ++i) {                          \
      const int c = i * 256 + tid;                                           \
      const int row = c >> 2;                                                \
      const int scb = (((c & 3) << 4)) ^ ((row & 3) << 4);                   \
      gload16(Ctx + (m0 + row) * 1024 + (k0) + (scb >> 1),                   \
              (unsigned short*)((char*)(la0 + (buf)*4096) + c * 16));        \
    }                                                                        \
    {                                                                        \
      const int row = tid >> 2;                                              \
      const int scb = (((tid & 3) << 4)) ^ ((row & 3) << 4);                 \
      gload16(Wo + (n0 + row) * 1024 + (k0) + (scb >> 1),                    \
              (unsigned short*)((char*)(lb0 + (buf)*2048) + tid * 16));      \
    }                                                                        \
  }

  STG_OUT(0, 0);
  __syncthreads();

  for (int kt = 0; kt < 32; ++kt) {
    const int cur = kt & 1;
    unsigned short* la = la0 + cur * 4096;
    unsigned short* lb = lb0 + cur * 2048;
    if (kt + 1 < 32) STG_OUT(cur ^ 1, (kt + 1) * 32);
    bf16x8 af[4], bfr[2];
#pragma unroll
    for (int m = 0; m < 4; ++m)
      af[m] = *reinterpret_cast<const bf16x8*>(
          (char*)la + (wm + m * 16 + l15) * 64 + (g16 ^ sx));
#pragma unroll
    for (int n = 0; n < 2; ++n)
      bfr[n] = *reinterpret_cast<const bf16x8*>(
          (char*)lb + (wn + n * 16 + l15) * 64 + (g16 ^ sx));
#pragma unroll
    for (int m = 0; m < 4; ++m)
#pragma unroll
      for (int n = 0; n < 2; ++n)
        acc[m][n] = mfma16(af[m], bfr[n], acc[m][n]);
    __syncthreads();
  }
#undef STG_OUT

  float* lwf = (float*)(ls + wave * 4096);
#pragma unroll
  for (int m = 0; m < 4; ++m)
#pragma unroll
    for (int n = 0; n < 2; ++n) {
      const float bb = bo[n0 + wn + n * 16 + l15];
#pragma unroll
      for (int r = 0; r < 4; ++r)
        lwf[(m * 16 + (g << 2) + r) * 32 + n * 16 + l15] = acc[m][n][r] + bb;
    }
  WAITLGKM();
  SCHEDB();
#pragma unroll
  for (int it = 0; it < 8; ++it) {
    const int rr = (lane >> 3) + it * 8;
    const int ck = (lane & 7) * 4;
    float4 v = *reinterpret_cast<const float4*>(&lwf[rr * 32 + ck]);
    *reinterpret_cast<float4*>(&Out[(m0 + wm + rr) * 1024 + n0 + wn + ck]) = v;
  }
}

// ---------------- causal flash attention (parity-split + safe dual) ------
// grid: 512 1-D, xcd = bh%8. Wave w: parity s=w>>2, row-group rg=w&3.
// Dual-step uses ONE per-wave lp buffer sequentially (B then A): shared
// kf QK loads and shared vf PV loads; no cross-wave buffer aliasing.

DEV void attn_stage128(const unsigned short* __restrict__ Kb,
                       const unsigned short* __restrict__ Vb,
                       unsigned short* lk, unsigned short* lv, int kv0,
                       int tid) {
#pragma unroll
  for (int i = 0; i < 2; ++i) {
    const int c = i * 512 + tid;            // 0..1023 chunks of 16B
    const int krow = c >> 3;                // 0..127
    const int kscb = ((c & 7) << 4) ^ ((krow & 7) << 4);
    gload16(Kb + (kv0 + krow) * 64 + (kscb >> 1),
            (unsigned short*)((char*)lk + c * 16));
    const int vrow = c >> 4;                // hd 0..63
    const int vscb = ((c & 15) << 4) ^ ((vrow & 7) << 4);
    gload16(Vb + vrow * 2048 + kv0 + (vscb >> 1),
            (unsigned short*)((char*)lv + c * 16));
  }
}

DEV void attn_step(const unsigned short* lk128, int s,
                   const unsigned short* lv128,
                   unsigned short (&lp)[16][64], const bf16x8 (&qf)[2],
                   f32x4 (&o)[4], float& lsum, int lane, int qloc, bool diag) {
  const int g = lane >> 4;
  const int l15 = lane & 15;
  f32x4 st[4];
  PRIO(1);
#pragma unroll
  for (int n = 0; n < 4; ++n) {
    f32x4 z = {};
    const int row = n * 16 + l15;
    const int sw = (row & 7) << 4;
#pragma unroll
    for (int kk = 0; kk < 2; ++kk) {
      bf16x8 kf = *reinterpret_cast<const bf16x8*>(
          (char*)lk128 + (s * 64 + row) * 128 + ((kk * 64 + (g << 4)) ^ sw));
      z = mfma16(kf, qf[kk], z);
    }
    st[n] = z;
  }
  PRIO(0);
  if (diag) {
#pragma unroll
    for (int n = 0; n < 4; ++n)
#pragma unroll
      for (int r = 0; r < 4; ++r)
        if (n * 16 + g * 4 + r > qloc) st[n][r] = -1e30f;
  }
  float rs = 0.f;
#pragma unroll
  for (int n = 0; n < 4; ++n)
#pragma unroll
    for (int r = 0; r < 4; ++r) {
      float p = exp2f(st[n][r]);
      st[n][r] = p;
      rs += p;
    }
  lsum += rs;
  const int psw = (l15 & 7) << 4;
#pragma unroll
  for (int n = 0; n < 4; ++n) {
    uint2 w;
    w.x = cvtpk(st[n][0], st[n][1]);
    w.y = cvtpk(st[n][2], st[n][3]);
    *reinterpret_cast<uint2*>(
        (char*)lp + l15 * 128 + (((n << 5) | (g << 3)) ^ psw)) = w;
  }
  WAITLGKM();
  SCHEDB();
  bf16x8 pb[2];
  pb[0] = *reinterpret_cast<const bf16x8*>(
      (char*)lp + l15 * 128 + (((g << 4)) ^ psw));
  pb[1] = *reinterpret_cast<const bf16x8*>(
      (char*)lp + l15 * 128 + ((64 + (g << 4)) ^ psw));
  PRIO(1);
#pragma unroll
  for (int h = 0; h < 4; ++h) {
    const int vr = h * 16 + l15;
    const int sw = (vr & 7) << 4;
#pragma unroll
    for (int kk = 0; kk < 2; ++kk) {
      bf16x8 vf = *reinterpret_cast<const bf16x8*>(
          (char*)lv128 + vr * 256 + ((s * 128 + kk * 64 + (g << 4)) ^ sw));
      o[h] = mfma16(vf, pb[kk], o[h]);
    }
  }
  PRIO(0);
}

// dual-step: shared kf QK + shared vf PV; ONE lp buffer used sequentially.
DEV void attn_step_dual(const unsigned short* lk128, int s,
                        const unsigned short* lv128,
                        unsigned short (&lp)[16][64],
                        const bf16x8 (&qfB)[2], const bf16x8 (&qfA)[2],
                        f32x4 (&oB)[4], f32x4 (&oA)[4], float& lsB,
                        float& lsA, int lane, int qloc, bool diagB,
                        bool diagA) {
  const int g = lane >> 4;
  const int l15 = lane & 15;
  f32x4 sB[4], sA[4];
  PRIO(1);
#pragma unroll
  for (int n = 0; n < 4; ++n) {
    f32x4 zB = {}, zA = {};
    const int row = n * 16 + l15;
    const int sw = (row & 7) << 4;
#pragma unroll
    for (int kk = 0; kk < 2; ++kk) {
      bf16x8 kf = *reinterpret_cast<const bf16x8*>(
          (char*)lk128 + (s * 64 + row) * 128 + ((kk * 64 + (g << 4)) ^ sw));
      zB = mfma16(kf, qfB[kk], zB);
      zA = mfma16(kf, qfA[kk], zA);
    }
    sB[n] = zB;
    sA[n] = zA;
  }
  PRIO(0);
  if (diagB) {
#pragma unroll
    for (int n = 0; n < 4; ++n)
#pragma unroll
      for (int r = 0; r < 4; ++r)
        if (n * 16 + g * 4 + r > qloc) sB[n][r] = -1e30f;
  }
  if (diagA) {
#pragma unroll
    for (int n = 0; n < 4; ++n)
#pragma unroll
      for (int r = 0; r < 4; ++r)
        if (n * 16 + g * 4 + r > qloc) sA[n][r] = -1e30f;
  }
  float rsB = 0.f, rsA = 0.f;
#pragma unroll
  for (int n = 0; n < 4; ++n)
#pragma unroll
    for (int r = 0; r < 4; ++r) {
      float pB = exp2f(sB[n][r]);
      float pA = exp2f(sA[n][r]);
      sB[n][r] = pB;
      sA[n][r] = pA;
      rsB += pB;
      rsA += pA;
    }
  lsB += rsB;
  lsA += rsA;
  const int psw = (l15 & 7) << 4;

  // B's P -> lp, read pbB into regs
#pragma unroll
  for (int n = 0; n < 4; ++n) {
    uint2 w;
    w.x = cvtpk(sB[n][0], sB[n][1]);
    w.y = cvtpk(sB[n][2], sB[n][3]);
    *reinterpret_cast<uint2*>(
        (char*)lp + l15 * 128 + (((n << 5) | (g << 3)) ^ psw)) = w;
  }
  WAITLGKM();
  SCHEDB();
  bf16x8 pbB[2];
  pbB[0] = *reinterpret_cast<const bf16x8*>(
      (char*)lp + l15 * 128 + (((g << 4)) ^ psw));
  pbB[1] = *reinterpret_cast<const bf16x8*>(
      (char*)lp + l15 * 128 + ((64 + (g << 4)) ^ psw));
  WAITLGKM();  // pbB in regs before overwrite (per-wave DS ordering + fence)
  SCHEDB();

  // A's P -> same lp, read pbA
#pragma unroll
  for (int n = 0; n < 4; ++n) {
    uint2 w;
    w.x = cvtpk(sA[n][0], sA[n][1]);
    w.y = cvtpk(sA[n][2], sA[n][3]);
    *reinterpret_cast<uint2*>(
        (char*)lp + l15 * 128 + (((n << 5) | (g << 3)) ^ psw)) = w;
  }
  WAITLGKM();
  SCHEDB();
  bf16x8 pbA[2];
  pbA[0] = *reinterpret_cast<const bf16x8*>(
      (char*)lp + l15 * 128 + (((g << 4)) ^ psw));
  pbA[1] = *reinterpret_cast<const bf16x8*>(
      (char*)lp + l15 * 128 + ((64 + (g << 4)) ^ psw));
  WAITLGKM();
  SCHEDB();

  // PV with shared vf loads feeding both tiles
  PRIO(1);
#pragma unroll
  for (int h = 0; h < 4; ++h) {
    const int vr = h * 16 + l15;
    const int sw = (vr & 7) << 4;
#pragma unroll
    for (int kk = 0; kk < 2; ++kk) {
      bf16x8 vf = *reinterpret_cast<const bf16x8*>(
          (char*)lv128 + vr * 256 + ((s * 128 + kk * 64 + (g << 4)) ^ sw));
      oB[h] = mfma16(vf, pbB[kk], oB[h]);
      oA[h] = mfma16(vf, pbA[kk], oA[h]);
    }
  }
  PRIO(0);
}

DEV void attn_epi(unsigned short* __restrict__ Ctx,
                  unsigned short (&lp)[16][64], const f32x4 (&o)[4],
                  float lsum, int b, int hh, int qbase, int lane) {
  float lt = lsum;
  lt += __shfl_xor(lt, 16);
  lt += __shfl_xor(lt, 32);
  const float inv = 1.f / lt;
  const int g = lane >> 4;
  const int l15 = lane & 15;
  const int psw = (l15 & 7) << 4;
#pragma unroll
  for (int h = 0; h < 4; ++h) {
    uint2 w;
    w.x = cvtpk(o[h][0] * inv, o[h][1] * inv);
    w.y = cvtpk(o[h][2] * inv, o[h][3] * inv);
    *reinterpret_cast<uint2*>(
        (char*)lp + l15 * 128 + (((h << 5) | (g << 3)) ^ psw)) = w;
  }
  WAITLGKM();
  SCHEDB();
#pragma unroll
  for (int it = 0; it < 2; ++it) {
    const int q = (lane >> 3) + it * 8;
    const int blk = (lane & 7) ^ (q & 7);
    uint4 v = *reinterpret_cast<const uint4*>((char*)lp + q * 128 + blk * 16);
    *reinterpret_cast<uint4*>(
        &Ctx[(b * 2048 + qbase + q) * 1024 + hh * 64 + ((lane & 7) << 3)]) = v;
  }
}

__global__ __launch_bounds__(512) void k_attn(
    const unsigned short* __restrict__ Q, const unsigned short* __restrict__ K,
    const unsigned short* __restrict__ Vt, unsigned short* __restrict__ Ctx) {
  __shared__ unsigned short lk[2][8192];    // K [128][64], double buffer
  __shared__ unsigned short lv[2][8192];    // V^T [64][128], double buffer
  __shared__ unsigned short lp[8][16][64];  // per-wave, XOR-swizzled

  const int tid = threadIdx.x, lane = tid & 63, wave = tid >> 6;
  const int id = blockIdx.x;
  const int xcd = id & 7, r4 = id >> 3;  // r4: 0..63
  const int ip = r4 & 15;
  const int bh = ((r4 >> 4) << 3) + xcd;

  const int qtA = ip;
  const int qtB = 31 - ip;
  const int nb = (qtB >> 1) + 1;

  const int s = wave >> 2;     // kv-parity of this wave
  const int rg = wave & 3;     // q row-group (16 rows) within 64-row tile
  const int l15 = lane & 15;
  const int qloc = rg * 16 + l15;

  const unsigned short* Kb = K + bh * 2048 * 64;
  const unsigned short* Vb = Vt + bh * 64 * 2048;

  bf16x8 qfB[2], qfA[2];
  {
    const unsigned short* qr =
        Q + (bh * 2048 + qtB * 64 + rg * 16 + l15) * 64 + ((lane >> 4) << 3);
    qfB[0] = *reinterpret_cast<const bf16x8*>(qr);
    qfB[1] = *reinterpret_cast<const bf16x8*>(qr + 32);
    qr = Q + (bh * 2048 + qtA * 64 + rg * 16 + l15) * 64 + ((lane >> 4) << 3);
    qfA[0] = *reinterpret_cast<const bf16x8*>(qr);
    qfA[1] = *reinterpret_cast<const bf16x8*>(qr + 32);
  }

  f32x4 oB[4] = {}, oA[4] = {};
  float lsB = 0.f, lsA = 0.f;

  attn_stage128(Kb, Vb, lk[0], lv[0], 0, tid);

  for (int t = 0; t < nb; ++t) {
    WAITVM(0);  // stage(t) fully landed (L2-resident, short drain)
    BAR();      // all waves done with compute(t-1); stage(t) visible
    if (t + 1 < nb)  // uniform branch; no redundant tail re-stage
      attn_stage128(Kb, Vb, lk[(t + 1) & 1], lv[(t + 1) & 1], (t + 1) * 128,
                    tid);
    SCHEDB();
    const unsigned short* lkc = lk[t & 1];
    const unsigned short* lvc = lv[t & 1];
    const int sub = 2 * t + s;  // this wave's parity sub-step
    const bool actB = (sub <= qtB), actA = (sub <= qtA);
    if (actB && actA)
      attn_step_dual(lkc, s, lvc, lp[wave], qfB, qfA, oB, oA, lsB, lsA, lane,
                     qloc, sub == qtB, sub == qtA);
    else if (actB)
      attn_step(lkc, s, lvc, lp[wave], qfB, oB, lsB, lane, qloc, sub == qtB);
  }

  // Drain in-flight DMA before overlaying lk and before endpgm.
  WAITVM(0);
  BAR();

  // waves 4-7 publish partials into lk overlay (XOR-swizzled, conflict-free)
  if (s == 1) {
    char* base = (char*)lk + (wave - 4) * 8192 + lane * 128;
    const int lx = lane & 7;
#pragma unroll
    for (int h = 0; h < 4; ++h) {
      *reinterpret_cast<f32x4*>(base + ((h ^ lx) << 4)) = oB[h];
      *reinterpret_cast<f32x4*>(base + (((4 + h) ^ lx) << 4)) = oA[h];
    }
    float2 lsp;
    lsp.x = lsB;
    lsp.y = lsA;
    *reinterpret_cast<float2*>((char*)lv + ((wave - 4) * 64 + lane) * 8) = lsp;
    WAITLGKM();  // ds_writes visible before the barrier
  }
  BAR();

  if (s == 0) {
    char* base = (char*)lk + wave * 8192 + lane * 128;
    const int lx = lane & 7;
#pragma unroll
    for (int h = 0; h < 4; ++h) {
      f32x4 pB = *reinterpret_cast<const f32x4*>(base + ((h ^ lx) << 4));
      f32x4 pA = *reinterpret_cast<const f32x4*>(base + (((4 + h) ^ lx) << 4));
      oB[h] += pB;
      oA[h] += pA;
    }
    float2 lsp =
        *reinterpret_cast<const float2*>((char*)lv + (wave * 64 + lane) * 8);
    lsB += lsp.x;
    lsA += lsp.y;
    WAITLGKM();

    const int b = bh >> 4, hh = bh & 15;
    attn_epi(Ctx, lp[wave], oB, lsB, b, hh, qtB * 64 + rg * 16, lane);
    attn_epi(Ctx, lp[wave + 4], oA, lsA, b, hh, qtA * 64 + rg * 16, lane);
  }
}

// ---------------- launch ----------------
extern "C" void kernel_launch(void* const* d_in, const int* in_sizes, int n_in,
                              void* d_out, int out_size, void* d_ws,
                              size_t ws_size, hipStream_t stream) {
  const float* x = (const float*)d_in[0];
  const float* Wq = (const float*)d_in[1];
  const float* bq = (const float*)d_in[2];
  const float* Wk = (const float*)d_in[3];
  const float* bk = (const float*)d_in[4];
  const float* Wv = (const float*)d_in[5];
  const float* bv = (const float*)d_in[6];
  const float* Wo = (const float*)d_in[7];
  const float* bo = (const float*)d_in[8];
  float* out = (float*)d_out;

  char* ws = (char*)d_ws;
  unsigned short* xb = (unsigned short*)(ws);                    // 8 MB
  unsigned short* wqb = (unsigned short*)(ws + (8u << 20));      // 2 MB
  unsigned short* wkb = (unsigned short*)(ws + (10u << 20));
  unsigned short* wvb = (unsigned short*)(ws + (12u << 20));
  unsigned short* wob = (unsigned short*)(ws + (14u << 20));
  unsigned short* Qb = (unsigned short*)(ws + (16u << 20));      // 8 MB
  unsigned short* Kb = (unsigned short*)(ws + (24u << 20));      // 8 MB
  unsigned short* Vtb = (unsigned short*)(ws + (32u << 20));     // 8 MB
  unsigned short* Ctx = (unsigned short*)(ws + (40u << 20));     // 8 MB

  k_cvt_all<<<8192, 256, 0, stream>>>(x, Wq, Wk, Wv, Wo, xb);

  k_gemm_qkv<<<512, 256, 0, stream>>>(xb, wqb, wkb, wvb, bq, bk, bv,
                                      Qb, Kb, Vtb);
  k_attn<<<512, 512, 0, stream>>>(Qb, Kb, Vtb, Ctx);
  k_gemm_out<<<512, 256, 0, stream>>>(Ctx, wob, bo, out);
}

// Round 21
// 106.361 us; speedup vs baseline: 1.0666x; 1.0666x over previous
//
#include <hip/hip_runtime.h>

// Fused MHA: x->QKV proj (bf16 MFMA) -> causal flash attn -> O proj.
// B=2, T=2048, D=1024, H=16, HD=64.
// FINAL (= round 18, session best 106.07us): fused QKV (X staged once for
// Q/K/V), parity-split KVBLK=128 flash attention (fixed-max exp2 softmax,
// XCD-aware decode, counted-DMA staging), 128x64 out-proj, fused cvt.

#define DEV __device__ __forceinline__

typedef __attribute__((ext_vector_type(8))) __bf16 bf16x8;
typedef __attribute__((ext_vector_type(4))) float f32x4;

DEV unsigned short f2bf(float f) {
  union { float f; unsigned u; } c;
  c.f = f;
  unsigned u = c.u + 0x7FFFu + ((c.u >> 16) & 1u);  // RTNE
  return (unsigned short)(u >> 16);
}

DEV unsigned cvtpk(float lo, float hi) {
  unsigned r;
  asm("v_cvt_pk_bf16_f32 %0, %1, %2" : "=v"(r) : "v"(lo), "v"(hi));
  return r;
}

DEV void gload16(const unsigned short* g, unsigned short* l) {
  __builtin_amdgcn_global_load_lds(
      (const __attribute__((address_space(1))) unsigned int*)g,
      (__attribute__((address_space(3))) unsigned int*)l, 16, 0, 0);
}

DEV f32x4 mfma16(bf16x8 a, bf16x8 b, f32x4 c) {
  return __builtin_amdgcn_mfma_f32_16x16x32_bf16(a, b, c, 0, 0, 0);
}

#define WAITVM(n) asm volatile("s_waitcnt vmcnt(" #n ")" ::: "memory")
#define WAITLGKM() asm volatile("s_waitcnt lgkmcnt(0)" ::: "memory")
#define BAR() __builtin_amdgcn_s_barrier()
#define SCHEDB() __builtin_amdgcn_sched_barrier(0)
#define PRIO(n) __builtin_amdgcn_s_setprio(n)

// ---------------- fp32 -> bf16 convert (all 5 tensors, one launch) -------
__global__ __launch_bounds__(256) void k_cvt_all(
    const float* __restrict__ x, const float* __restrict__ wq,
    const float* __restrict__ wk, const float* __restrict__ wv,
    const float* __restrict__ wo, unsigned short* __restrict__ dst) {
  int i = blockIdx.x * blockDim.x + threadIdx.x;  // float4 index
  const float* s;
  int off;
  if (i < 1048576) {
    s = x; off = i;
  } else {
    int j = i - 1048576;
    int w = j >> 18;
    off = j & 262143;
    s = (w == 0) ? wq : (w == 1) ? wk : (w == 2) ? wv : wo;
  }
  float4 v = reinterpret_cast<const float4*>(s)[off];
  uint2 o;
  o.x = (unsigned)f2bf(v.x) | ((unsigned)f2bf(v.y) << 16);
  o.y = (unsigned)f2bf(v.z) | ((unsigned)f2bf(v.w) << 16);
  reinterpret_cast<uint2*>(dst)[i] = o;
}

// ---------------- FUSED QKV projection (128x64 tiles, 3 modes) ----------
__global__ __launch_bounds__(256) void k_gemm_qkv(
    const unsigned short* __restrict__ X, const unsigned short* __restrict__ Wq,
    const unsigned short* __restrict__ Wk, const unsigned short* __restrict__ Wv,
    const float* __restrict__ bq, const float* __restrict__ bk,
    const float* __restrict__ bv, unsigned short* __restrict__ Qo,
    unsigned short* __restrict__ Ko, unsigned short* __restrict__ Vo) {
  __shared__ unsigned short ls[20480];  // X 2x4096 | Wq 2x2048 | Wk | Wv
  unsigned short* la0 = ls;
  unsigned short* lbq = ls + 8192;
  unsigned short* lbk = ls + 12288;
  unsigned short* lbv = ls + 16384;

  const int id = blockIdx.x;
  const int xcd = id & 7, s4 = id >> 3;
  const int bx = ((s4 >> 3) & 7) * 2 + (xcd & 1);  // 0..15
  const int by = (s4 & 7) * 4 + (xcd >> 1);        // 0..31
  const int m0 = by * 128, n0 = bx * 64;

  const int tid = threadIdx.x;
  const int lane = tid & 63, wave = tid >> 6;
  const int l15 = lane & 15, g = lane >> 4;
  const int wm = (wave >> 1) * 64, wn = (wave & 1) * 32;
  const int g16 = g << 4;
  const int sx = (lane & 3) << 4;

  f32x4 a0[4][2] = {}, a1[4][2] = {}, a2[4][2] = {};

#define STG_QKV(buf, k0)                                                     \
  {                                                                          \
    _Pragma("unroll") for (int i = 0; i < 2; ++i) {                          \
      const int c = i * 256 + tid;                                           \
      const int row = c >> 2;                                                \
      const int scb = ((c & 3) << 4) ^ ((row & 3) << 4);                     \
      gload16(X + (m0 + row) * 1024 + (k0) + (scb >> 1),                     \
              (unsigned short*)((char*)(la0 + (buf)*4096) + c * 16));        \
    }                                                                        \
    {                                                                        \
      const int row = tid >> 2;                                              \
      const int scb = ((tid & 3) << 4) ^ ((row & 3) << 4);                   \
      const int go = (n0 + row) * 1024 + (k0) + (scb >> 1);                  \
      gload16(Wq + go,                                                       \
              (unsigned short*)((char*)(lbq + (buf)*2048) + tid * 16));      \
      gload16(Wk + go,                                                       \
              (unsigned short*)((char*)(lbk + (buf)*2048) + tid * 16));      \
      gload16(Wv + go,                                                       \
              (unsigned short*)((char*)(lbv + (buf)*2048) + tid * 16));      \
    }                                                                        \
  }

  STG_QKV(0, 0);
  __syncthreads();

  for (int kt = 0; kt < 32; ++kt) {
    const int cur = kt & 1;
    if (kt + 1 < 32) STG_QKV(cur ^ 1, (kt + 1) * 32);
    unsigned short* la = la0 + cur * 4096;
    bf16x8 af[4];
#pragma unroll
    for (int m = 0; m < 4; ++m)
      af[m] = *reinterpret_cast<const bf16x8*>(
          (char*)la + (wm + m * 16 + l15) * 64 + (g16 ^ sx));
    {
      unsigned short* lb = lbq + cur * 2048;
      bf16x8 bfr[2];
#pragma unroll
      for (int n = 0; n < 2; ++n)
        bfr[n] = *reinterpret_cast<const bf16x8*>(
            (char*)lb + (wn + n * 16 + l15) * 64 + (g16 ^ sx));
#pragma unroll
      for (int m = 0; m < 4; ++m)
#pragma unroll
        for (int n = 0; n < 2; ++n) a0[m][n] = mfma16(af[m], bfr[n], a0[m][n]);
    }
    {
      unsigned short* lb = lbk + cur * 2048;
      bf16x8 bfr[2];
#pragma unroll
      for (int n = 0; n < 2; ++n)
        bfr[n] = *reinterpret_cast<const bf16x8*>(
            (char*)lb + (wn + n * 16 + l15) * 64 + (g16 ^ sx));
#pragma unroll
      for (int m = 0; m < 4; ++m)
#pragma unroll
        for (int n = 0; n < 2; ++n) a1[m][n] = mfma16(af[m], bfr[n], a1[m][n]);
    }
    {
      unsigned short* lb = lbv + cur * 2048;
      bf16x8 bfr[2];
#pragma unroll
      for (int n = 0; n < 2; ++n)
        bfr[n] = *reinterpret_cast<const bf16x8*>(
            (char*)lb + (wn + n * 16 + l15) * 64 + (g16 ^ sx));
#pragma unroll
      for (int m = 0; m < 4; ++m)
#pragma unroll
        for (int n = 0; n < 2; ++n) a2[m][n] = mfma16(af[m], bfr[n], a2[m][n]);
    }
    __syncthreads();
  }
#undef STG_QKV

  // ---- epilogues (per-wave 4KB lw; modes sequential with lgkm fences) ----
  unsigned short* lw = ls + wave * 2048;
  const int h = (n0 + wn) >> 6;
  const int hd0 = (n0 + wn) & 63;       // 0 or 32
  const int rb = m0 + wm;
  const int b = rb >> 11;
  const int tb0 = rb & 2047;

  // Q (scaled) then K: lw[64 t][32 hd]
#pragma unroll
  for (int mode = 0; mode < 2; ++mode) {
    const float* bias = mode ? bk : bq;
    const float sc = mode ? 1.0f : 0.180336880f;  // 0.125 * log2(e)
    unsigned short* dst = mode ? Ko : Qo;
    WAITLGKM();  // prior mode's lw reads complete before overwrite
#pragma unroll
    for (int m = 0; m < 4; ++m)
#pragma unroll
      for (int n = 0; n < 2; ++n) {
        const float bb = bias[n0 + wn + n * 16 + l15];
        const f32x4 av = mode ? a1[m][n] : a0[m][n];
#pragma unroll
        for (int r = 0; r < 4; ++r)
          lw[(m * 16 + (g << 2) + r) * 32 + n * 16 + l15] =
              f2bf((av[r] + bb) * sc);
      }
    WAITLGKM();
    SCHEDB();
#pragma unroll
    for (int it = 0; it < 4; ++it) {
      const int rr = (lane >> 2) + it * 16;
      const int ck = (lane & 3) * 8;
      uint4 v = *reinterpret_cast<const uint4*>(&lw[rr * 32 + ck]);
      *reinterpret_cast<uint4*>(
          &dst[(((b << 4) + h) * 2048 + tb0 + rr) * 64 + hd0 + ck]) = v;
    }
  }

  // V^T: lw[32 hd][64 t]
  WAITLGKM();
#pragma unroll
  for (int m = 0; m < 4; ++m)
#pragma unroll
    for (int n = 0; n < 2; ++n) {
      const float bb = bv[n0 + wn + n * 16 + l15];
      uint2 w;
      w.x = cvtpk(a2[m][n][0] + bb, a2[m][n][1] + bb);
      w.y = cvtpk(a2[m][n][2] + bb, a2[m][n][3] + bb);
      *reinterpret_cast<uint2*>(&lw[(n * 16 + l15) * 64 + m * 16 + (g << 2)]) =
          w;
    }
  WAITLGKM();
  SCHEDB();
#pragma unroll
  for (int it = 0; it < 4; ++it) {
    const int hdr = (lane >> 3) + it * 8;
    const int ck = (lane & 7) * 8;
    uint4 v = *reinterpret_cast<const uint4*>(&lw[hdr * 64 + ck]);
    *reinterpret_cast<uint4*>(
        &Vo[(((b << 4) + h) * 64 + hd0 + hdr) * 2048 + tb0 + ck]) = v;
  }
}

// ---------------- output projection (128x64 tiles, fp32 out + bias) ------
__global__ __launch_bounds__(256) void k_gemm_out(
    const unsigned short* __restrict__ Ctx, const unsigned short* __restrict__ Wo,
    const float* __restrict__ bo, float* __restrict__ Out) {
  __shared__ unsigned short ls[16384];
  unsigned short* la0 = ls;
  unsigned short* lb0 = ls + 8192;
  const int id = blockIdx.x;
  const int xcd = id & 7, s4 = id >> 3;            // s4: 0..63
  const int bx = ((s4 >> 3) & 7) * 2 + (xcd & 1);  // 0..15
  const int by = (s4 & 7) * 4 + (xcd >> 1);        // 0..31
  const int tid = threadIdx.x;
  const int lane = tid & 63, wave = tid >> 6;
  const int l15 = lane & 15, g = lane >> 4;
  const int m0 = by * 128, n0 = bx * 64;
  const int wm = (wave >> 1) * 64, wn = (wave & 1) * 32;
  const int g16 = (g << 4);
  const int sx = (lane & 3) << 4;
  f32x4 acc[4][2] = {};

#define STG_OUT(buf, k0)                                                     \
  {                                                                          \
    _Pragma("unroll") for (int i = 0; i < 2; ++i) {                          \
      const int c = i * 256 + tid;                                           \
      const int row = c >> 2;                                                \
      const int scb = (((c & 3) << 4)) ^ ((row & 3) << 4);                   \
      gload16(Ctx + (m0 + row) * 1024 + (k0) + (scb >> 1),                   \
              (unsigned short*)((char*)(la0 + (buf)*4096) + c * 16));        \
    }                                                                        \
    {                                                                        \
      const int row = tid >> 2;                                              \
      const int scb = (((tid & 3) << 4)) ^ ((row & 3) << 4);                 \
      gload16(Wo + (n0 + row) * 1024 + (k0) + (scb >> 1),                    \
              (unsigned short*)((char*)(lb0 + (buf)*2048) + tid * 16));      \
    }                                                                        \
  }

  STG_OUT(0, 0);
  __syncthreads();

  for (int kt = 0; kt < 32; ++kt) {
    const int cur = kt & 1;
    unsigned short* la = la0 + cur * 4096;
    unsigned short* lb = lb0 + cur * 2048;
    if (kt + 1 < 32) STG_OUT(cur ^ 1, (kt + 1) * 32);
    bf16x8 af[4], bfr[2];
#pragma unroll
    for (int m = 0; m < 4; ++m)
      af[m] = *reinterpret_cast<const bf16x8*>(
          (char*)la + (wm + m * 16 + l15) * 64 + (g16 ^ sx));
#pragma unroll
    for (int n = 0; n < 2; ++n)
      bfr[n] = *reinterpret_cast<const bf16x8*>(
          (char*)lb + (wn + n * 16 + l15) * 64 + (g16 ^ sx));
#pragma unroll
    for (int m = 0; m < 4; ++m)
#pragma unroll
      for (int n = 0; n < 2; ++n)
        acc[m][n] = mfma16(af[m], bfr[n], acc[m][n]);
    __syncthreads();
  }
#undef STG_OUT

  float* lwf = (float*)(ls + wave * 4096);
#pragma unroll
  for (int m = 0; m < 4; ++m)
#pragma unroll
    for (int n = 0; n < 2; ++n) {
      const float bb = bo[n0 + wn + n * 16 + l15];
#pragma unroll
      for (int r = 0; r < 4; ++r)
        lwf[(m * 16 + (g << 2) + r) * 32 + n * 16 + l15] = acc[m][n][r] + bb;
    }
  WAITLGKM();
  SCHEDB();
#pragma unroll
  for (int it = 0; it < 8; ++it) {
    const int rr = (lane >> 3) + it * 8;
    const int ck = (lane & 7) * 4;
    float4 v = *reinterpret_cast<const float4*>(&lwf[rr * 32 + ck]);
    *reinterpret_cast<float4*>(&Out[(m0 + wm + rr) * 1024 + n0 + wn + ck]) = v;
  }
}

// ---------------- causal flash attention (parity-split, KVBLK=128) -------
// grid: 512 1-D, xcd = bh%8. Wave w: parity s=w>>2, row-group rg=w&3.
// Each wave handles sub-steps of its parity for BOTH q-tiles (B=31-ip,
// A=ip). Partials (O, lsum) combined across wave pairs (w, w+4) via
// swizzled LDS overlay.

DEV void attn_stage128(const unsigned short* __restrict__ Kb,
                       const unsigned short* __restrict__ Vb,
                       unsigned short* lk, unsigned short* lv, int kv0,
                       int tid) {
#pragma unroll
  for (int i = 0; i < 2; ++i) {
    const int c = i * 512 + tid;            // 0..1023 chunks of 16B
    const int krow = c >> 3;                // 0..127
    const int kscb = ((c & 7) << 4) ^ ((krow & 7) << 4);
    gload16(Kb + (kv0 + krow) * 64 + (kscb >> 1),
            (unsigned short*)((char*)lk + c * 16));
    const int vrow = c >> 4;                // hd 0..63
    const int vscb = ((c & 15) << 4) ^ ((vrow & 7) << 4);
    gload16(Vb + vrow * 2048 + kv0 + (vscb >> 1),
            (unsigned short*)((char*)lv + c * 16));
  }
}

DEV void attn_step(const unsigned short* lk128, int s,
                   const unsigned short* lv128,
                   unsigned short (&lp)[16][64], const bf16x8 (&qf)[2],
                   f32x4 (&o)[4], float& lsum, int lane, int qloc, bool diag) {
  const int g = lane >> 4;
  const int l15 = lane & 15;
  f32x4 st[4];
  PRIO(1);
#pragma unroll
  for (int n = 0; n < 4; ++n) {
    f32x4 z = {};
    const int row = n * 16 + l15;
    const int sw = (row & 7) << 4;
#pragma unroll
    for (int kk = 0; kk < 2; ++kk) {
      bf16x8 kf = *reinterpret_cast<const bf16x8*>(
          (char*)lk128 + (s * 64 + row) * 128 + ((kk * 64 + (g << 4)) ^ sw));
      z = mfma16(kf, qf[kk], z);
    }
    st[n] = z;
  }
  PRIO(0);
  if (diag) {
#pragma unroll
    for (int n = 0; n < 4; ++n)
#pragma unroll
      for (int r = 0; r < 4; ++r)
        if (n * 16 + g * 4 + r > qloc) st[n][r] = -1e30f;
  }
  float rs = 0.f;
#pragma unroll
  for (int n = 0; n < 4; ++n)
#pragma unroll
    for (int r = 0; r < 4; ++r) {
      float p = exp2f(st[n][r]);
      st[n][r] = p;
      rs += p;
    }
  lsum += rs;
  const int psw = (l15 & 7) << 4;
#pragma unroll
  for (int n = 0; n < 4; ++n) {
    uint2 w;
    w.x = cvtpk(st[n][0], st[n][1]);
    w.y = cvtpk(st[n][2], st[n][3]);
    *reinterpret_cast<uint2*>(
        (char*)lp + l15 * 128 + (((n << 5) | (g << 3)) ^ psw)) = w;
  }
  WAITLGKM();
  SCHEDB();
  bf16x8 pb[2];
  pb[0] = *reinterpret_cast<const bf16x8*>(
      (char*)lp + l15 * 128 + (((g << 4)) ^ psw));
  pb[1] = *reinterpret_cast<const bf16x8*>(
      (char*)lp + l15 * 128 + ((64 + (g << 4)) ^ psw));
  PRIO(1);
#pragma unroll
  for (int h = 0; h < 4; ++h) {
    const int vr = h * 16 + l15;
    const int sw = (vr & 7) << 4;
#pragma unroll
    for (int kk = 0; kk < 2; ++kk) {
      bf16x8 vf = *reinterpret_cast<const bf16x8*>(
          (char*)lv128 + vr * 256 + ((s * 128 + kk * 64 + (g << 4)) ^ sw));
      o[h] = mfma16(vf, pb[kk], o[h]);
    }
  }
  PRIO(0);
}

DEV void attn_epi(unsigned short* __restrict__ Ctx,
                  unsigned short (&lp)[16][64], const f32x4 (&o)[4],
                  float lsum, int b, int hh, int qbase, int lane) {
  float lt = lsum;
  lt += __shfl_xor(lt, 16);
  lt += __shfl_xor(lt, 32);
  const float inv = 1.f / lt;
  const int g = lane >> 4;
  const int l15 = lane & 15;
  const int psw = (l15 & 7) << 4;
#pragma unroll
  for (int h = 0; h < 4; ++h) {
    uint2 w;
    w.x = cvtpk(o[h][0] * inv, o[h][1] * inv);
    w.y = cvtpk(o[h][2] * inv, o[h][3] * inv);
    *reinterpret_cast<uint2*>(
        (char*)lp + l15 * 128 + (((h << 5) | (g << 3)) ^ psw)) = w;
  }
  WAITLGKM();
  SCHEDB();
#pragma unroll
  for (int it = 0; it < 2; ++it) {
    const int q = (lane >> 3) + it * 8;
    const int blk = (lane & 7) ^ (q & 7);
    uint4 v = *reinterpret_cast<const uint4*>((char*)lp + q * 128 + blk * 16);
    *reinterpret_cast<uint4*>(
        &Ctx[(b * 2048 + qbase + q) * 1024 + hh * 64 + ((lane & 7) << 3)]) = v;
  }
}

__global__ __launch_bounds__(512) void k_attn(
    const unsigned short* __restrict__ Q, const unsigned short* __restrict__ K,
    const unsigned short* __restrict__ Vt, unsigned short* __restrict__ Ctx) {
  __shared__ unsigned short lk[2][8192];    // K [128][64], double buffer
  __shared__ unsigned short lv[2][8192];    // V^T [64][128], double buffer
  __shared__ unsigned short lp[8][16][64];  // per-wave, XOR-swizzled

  const int tid = threadIdx.x, lane = tid & 63, wave = tid >> 6;
  const int id = blockIdx.x;
  const int xcd = id & 7, r4 = id >> 3;  // r4: 0..63
  const int ip = r4 & 15;
  const int bh = ((r4 >> 4) << 3) + xcd;

  const int qtA = ip;
  const int qtB = 31 - ip;
  const int nb = (qtB >> 1) + 1;

  const int s = wave >> 2;     // kv-parity of this wave
  const int rg = wave & 3;     // q row-group (16 rows) within 64-row tile
  const int l15 = lane & 15;
  const int qloc = rg * 16 + l15;

  const unsigned short* Kb = K + bh * 2048 * 64;
  const unsigned short* Vb = Vt + bh * 64 * 2048;

  bf16x8 qfB[2], qfA[2];
  {
    const unsigned short* qr =
        Q + (bh * 2048 + qtB * 64 + rg * 16 + l15) * 64 + ((lane >> 4) << 3);
    qfB[0] = *reinterpret_cast<const bf16x8*>(qr);
    qfB[1] = *reinterpret_cast<const bf16x8*>(qr + 32);
    qr = Q + (bh * 2048 + qtA * 64 + rg * 16 + l15) * 64 + ((lane >> 4) << 3);
    qfA[0] = *reinterpret_cast<const bf16x8*>(qr);
    qfA[1] = *reinterpret_cast<const bf16x8*>(qr + 32);
  }

  f32x4 oB[4] = {}, oA[4] = {};
  float lsB = 0.f, lsA = 0.f;

  attn_stage128(Kb, Vb, lk[0], lv[0], 0, tid);

  for (int t = 0; t < nb; ++t) {
    WAITVM(0);  // stage(t) fully landed (L2-resident, short drain)
    BAR();      // all waves done with compute(t-1); stage(t) visible
    if (t + 1 < nb)  // uniform branch; no redundant tail re-stage
      attn_stage128(Kb, Vb, lk[(t + 1) & 1], lv[(t + 1) & 1], (t + 1) * 128,
                    tid);
    SCHEDB();
    const unsigned short* lkc = lk[t & 1];
    const unsigned short* lvc = lv[t & 1];
    const int sub = 2 * t + s;  // this wave's parity sub-step
    if (sub <= qtB)
      attn_step(lkc, s, lvc, lp[wave], qfB, oB, lsB, lane, qloc, sub == qtB);
    if (sub <= qtA)
      attn_step(lkc, s, lvc, lp[wave], qfA, oA, lsA, lane, qloc, sub == qtA);
  }

  // Drain in-flight DMA before overlaying lk and before endpgm.
  WAITVM(0);
  BAR();

  // waves 4-7 publish partials into lk overlay (XOR-swizzled, conflict-free)
  if (s == 1) {
    char* base = (char*)lk + (wave - 4) * 8192 + lane * 128;
    const int lx = lane & 7;
#pragma unroll
    for (int h = 0; h < 4; ++h) {
      *reinterpret_cast<f32x4*>(base + ((h ^ lx) << 4)) = oB[h];
      *reinterpret_cast<f32x4*>(base + (((4 + h) ^ lx) << 4)) = oA[h];
    }
    float2 lsp;
    lsp.x = lsB;
    lsp.y = lsA;
    *reinterpret_cast<float2*>((char*)lv + ((wave - 4) * 64 + lane) * 8) = lsp;
    WAITLGKM();  // ds_writes visible before the barrier
  }
  BAR();

  if (s == 0) {
    char* base = (char*)lk + wave * 8192 + lane * 128;
    const int lx = lane & 7;
#pragma unroll
    for (int h = 0; h < 4; ++h) {
      f32x4 pB = *reinterpret_cast<const f32x4*>(base + ((h ^ lx) << 4));
      f32x4 pA = *reinterpret_cast<const f32x4*>(base + (((4 + h) ^ lx) << 4));
      oB[h] += pB;
      oA[h] += pA;
    }
    float2 lsp =
        *reinterpret_cast<const float2*>((char*)lv + (wave * 64 + lane) * 8);
    lsB += lsp.x;
    lsA += lsp.y;
    WAITLGKM();

    const int b = bh >> 4, hh = bh & 15;
    attn_epi(Ctx, lp[wave], oB, lsB, b, hh, qtB * 64 + rg * 16, lane);
    attn_epi(Ctx, lp[wave + 4], oA, lsA, b, hh, qtA * 64 + rg * 16, lane);
  }
}

// ---------------- launch ----------------
extern "C" void kernel_launch(void* const* d_in, const int* in_sizes, int n_in,
                              void* d_out, int out_size, void* d_ws,
                              size_t ws_size, hipStream_t stream) {
  const float* x = (const float*)d_in[0];
  const float* Wq = (const float*)d_in[1];
  const float* bq = (const float*)d_in[2];
  const float* Wk = (const float*)d_in[3];
  const float* bk = (const float*)d_in[4];
  const float* Wv = (const float*)d_in[5];
  const float* bv = (const float*)d_in[6];
  const float* Wo = (const float*)d_in[7];
  const float* bo = (const float*)d_in[8];
  float* out = (float*)d_out;

  char* ws = (char*)d_ws;
  unsigned short* xb = (unsigned short*)(ws);                    // 8 MB
  unsigned short* wqb = (unsigned short*)(ws + (8u << 20));      // 2 MB
  unsigned short* wkb = (unsigned short*)(ws + (10u << 20));
  unsigned short* wvb = (unsigned short*)(ws + (12u << 20));
  unsigned short* wob = (unsigned short*)(ws + (14u << 20));
  unsigned short* Qb = (unsigned short*)(ws + (16u << 20));      // 8 MB
  unsigned short* Kb = (unsigned short*)(ws + (24u << 20));      // 8 MB
  unsigned short* Vtb = (unsigned short*)(ws + (32u << 20));     // 8 MB
  unsigned short* Ctx = (unsigned short*)(ws + (40u << 20));     // 8 MB

  k_cvt_all<<<8192, 256, 0, stream>>>(x, Wq, Wk, Wv, Wo, xb);

  k_gemm_qkv<<<512, 256, 0, stream>>>(xb, wqb, wkb, wvb, bq, bk, bv,
                                      Qb, Kb, Vtb);
  k_attn<<<512, 512, 0, stream>>>(Qb, Kb, Vtb, Ctx);
  k_gemm_out<<<512, 256, 0, stream>>>(Ctx, wob, bo, out);
}